// Round 7
// baseline (1241.912 us; speedup 1.0000x reference)
//
#include <hip/hip_runtime.h>
#include <hip/hip_bf16.h>
#include <cstdint>
#include <cstddef>

#define N_MOLS 256
#define N_PER  32
#define NN     8192
#define EDGES  253952
#define SDIM_  256
#define EDIM_  32
#define NAF_   16
#define LAYERS_ 5

typedef __attribute__((ext_vector_type(8)))  short bf16x8;
typedef __attribute__((ext_vector_type(16))) float f32x16;

__device__ __forceinline__ float silu_f(float x) {
    return x / (1.f + __expf(-x));
}
__device__ __forceinline__ short bfc(float f) {
    __hip_bfloat16 h = __float2bfloat16(f);
    return __builtin_bit_cast(short, h);
}
__device__ __forceinline__ float bf2f(short h) {
    union { uint32_t u; float f; } v; v.u = ((uint32_t)(unsigned short)h) << 16; return v.f;
}
#define ONEBF ((short)0x3F80)

// ---------------------------------------------------------------------------
// node init: h = [x|z]@Wam+bam; s = h[:,:256]; pos = rot[mol]@h[:,256:259]
// ---------------------------------------------------------------------------
__global__ __launch_bounds__(256) void node_init(
    const float* __restrict__ x, const float* __restrict__ z,
    const float* __restrict__ rot, const float* __restrict__ Wam,
    const float* __restrict__ bam, float* __restrict__ s, float* __restrict__ pos)
{
    const int n = blockIdx.x, t = threadIdx.x;
    __shared__ float xz[80];
    __shared__ float praw[3];
    if (t < 16)      xz[t] = x[n * 16 + t];
    else if (t < 80) xz[t] = z[n * 64 + (t - 16)];
    __syncthreads();
    float acc = bam[t];
    #pragma unroll 8
    for (int k = 0; k < 80; ++k) acc += xz[k] * Wam[k * 259 + t];
    s[(size_t)n * SDIM_ + t] = acc;
    if (t < 3) {
        const int j2 = 256 + t;
        float a2 = bam[j2];
        for (int k = 0; k < 80; ++k) a2 += xz[k] * Wam[k * 259 + j2];
        praw[t] = a2;
    }
    __syncthreads();
    if (t < 3) {
        const int mol = n >> 5;
        float p = 0.f;
        for (int jj = 0; jj < 3; ++jj) p += rot[mol * 9 + t * 3 + jj] * praw[jj];
        pos[n * 3 + t] = p;
    }
}

// ---------------------------------------------------------------------------
// edge feature init (bf16 out), tgt-major: e[((mol*32+n)*31+rr)*32+c]
// ---------------------------------------------------------------------------
__global__ __launch_bounds__(256) void edge_init2(
    const float* __restrict__ ea, const float* __restrict__ Wbm,
    const float* __restrict__ bbm, short* __restrict__ ebuf)
{
    const int tile = blockIdx.x;          // mol*32 + n
    const int mol = tile >> 5, n = tile & 31;
    const int t = threadIdx.x;
    for (int i = t; i < 31 * 32; i += 256) {
        const int rr = i >> 5, c = i & 31;
        const int s_ = rr + (rr >= n ? 1 : 0);
        const int ge = (mol * 32 + s_) * 31 + (n - (n > s_ ? 1 : 0));
        float acc = bbm[c];
        #pragma unroll
        for (int k = 0; k < 5; ++k) acc += ea[(size_t)ge * 5 + k] * Wbm[k * 32 + c];
        ebuf[(size_t)tile * 31 * 32 + i] = bfc(acc);
    }
}

// ---------------------------------------------------------------------------
// bf16 MFMA GEMM, 64x64 tile, 4 waves each 32x32 quadrant.
// ABF: A bf16; OUTBF: C bf16; POSTAIL: blocks (x==1,y<48) do pos += pd/31.
// ---------------------------------------------------------------------------
template<int ACT, int ACCUM, int POSTAIL, int ABF, int OUTBF>
__global__ __launch_bounds__(256) void gemm_mfma(
    const void* __restrict__ Av, const float* __restrict__ B,
    void* __restrict__ Cv, const float* __restrict__ bias,
    int K, int N, int ldb, float alpha,
    float* __restrict__ pos, const float* __restrict__ pd)
{
    const int n0 = blockIdx.x * 64, m0 = blockIdx.y * 64;
    const int t = threadIdx.x;
    const int wave = t >> 6, lane = t & 63;
    const int l = lane & 31, half = lane >> 5;
    const int wm = wave & 1, wn = wave >> 1;
    __shared__ __align__(16) short sA[64][40];
    __shared__ __align__(16) short sBt[64][40];
    f32x16 acc = {};
    const int mA = t >> 2, koA = (t & 3) * 8;
    const int krB = t >> 3, ncB = (t & 7) * 8;
    for (int k0 = 0; k0 < K; k0 += 32) {
        if (ABF) {
            const short* ap = (const short*)Av + (size_t)(m0 + mA) * K + k0 + koA;
            *(bf16x8*)&sA[mA][koA] = *(const bf16x8*)(ap);
        } else {
            const float* ap = (const float*)Av + (size_t)(m0 + mA) * K + k0 + koA;
            const float4 a0 = *(const float4*)(ap);
            const float4 a1 = *(const float4*)(ap + 4);
            bf16x8 p0;
            p0[0]=bfc(a0.x); p0[1]=bfc(a0.y); p0[2]=bfc(a0.z); p0[3]=bfc(a0.w);
            p0[4]=bfc(a1.x); p0[5]=bfc(a1.y); p0[6]=bfc(a1.z); p0[7]=bfc(a1.w);
            *(bf16x8*)&sA[mA][koA] = p0;
        }
        {
            const float* bp = B + (size_t)(k0 + krB) * ldb + n0 + ncB;
            const float4 b0 = *(const float4*)(bp);
            const float4 b1_ = *(const float4*)(bp + 4);
            sBt[ncB + 0][krB] = bfc(b0.x);  sBt[ncB + 1][krB] = bfc(b0.y);
            sBt[ncB + 2][krB] = bfc(b0.z);  sBt[ncB + 3][krB] = bfc(b0.w);
            sBt[ncB + 4][krB] = bfc(b1_.x); sBt[ncB + 5][krB] = bfc(b1_.y);
            sBt[ncB + 6][krB] = bfc(b1_.z); sBt[ncB + 7][krB] = bfc(b1_.w);
        }
        __syncthreads();
        #pragma unroll
        for (int ks = 0; ks < 2; ++ks) {
            const bf16x8 bfrag = *(const bf16x8*)&sBt[wn * 32 + l][ks * 16 + half * 8];
            const bf16x8 afr   = *(const bf16x8*)&sA[wm * 32 + l][ks * 16 + half * 8];
            acc = __builtin_amdgcn_mfma_f32_32x32x16_bf16(afr, bfrag, acc, 0,0,0);
        }
        __syncthreads();
    }
    const int n = n0 + wn * 32 + l;
    const float bv = bias ? bias[n] : 0.f;
    #pragma unroll
    for (int r = 0; r < 16; ++r) {
        const int row = (r & 3) + 8 * (r >> 2) + 4 * half;
        const int m = m0 + wm * 32 + row;
        float v = alpha * acc[r] + bv;
        if (ACT) v = silu_f(v);
        if (OUTBF) ((short*)Cv)[(size_t)m * N + n] = bfc(v);
        else if (ACCUM) ((float*)Cv)[(size_t)m * N + n] += v;
        else            ((float*)Cv)[(size_t)m * N + n] = v;
    }
    if (POSTAIL && blockIdx.x == 1 && blockIdx.y < 48) {
        const int i = (blockIdx.y * 256 + t) * 2;
        pos[i]     += pd[i]     * (1.f / 31.f);
        pos[i + 1] += pd[i + 1] * (1.f / 31.f);
    }
}

// ---------------------------------------------------------------------------
// Dual GEMM (bf16 out), 64x64 tiles: SA = s@W1a, SB = s@W1b. grid (8,128).
// ---------------------------------------------------------------------------
__global__ __launch_bounds__(256) void gemm_dual(
    const float* __restrict__ A, const float* __restrict__ B0,
    const float* __restrict__ B1, short* __restrict__ C0, short* __restrict__ C1)
{
    const int K = 256, N = 256, ldb = 256;
    const float* B = (blockIdx.x < 4) ? B0 : B1;
    short* C = (blockIdx.x < 4) ? C0 : C1;
    const int n0 = (blockIdx.x & 3) * 64, m0 = blockIdx.y * 64;
    const int t = threadIdx.x;
    const int wave = t >> 6, lane = t & 63;
    const int l = lane & 31, half = lane >> 5;
    const int wm = wave & 1, wn = wave >> 1;
    __shared__ __align__(16) short sA[64][40];
    __shared__ __align__(16) short sBt[64][40];
    f32x16 acc = {};
    const int mA = t >> 2, koA = (t & 3) * 8;
    const int krB = t >> 3, ncB = (t & 7) * 8;
    for (int k0 = 0; k0 < K; k0 += 32) {
        {
            const float* ap = A + (size_t)(m0 + mA) * K + k0 + koA;
            const float4 a0 = *(const float4*)(ap);
            const float4 a1 = *(const float4*)(ap + 4);
            bf16x8 p0;
            p0[0]=bfc(a0.x); p0[1]=bfc(a0.y); p0[2]=bfc(a0.z); p0[3]=bfc(a0.w);
            p0[4]=bfc(a1.x); p0[5]=bfc(a1.y); p0[6]=bfc(a1.z); p0[7]=bfc(a1.w);
            *(bf16x8*)&sA[mA][koA] = p0;
        }
        {
            const float* bp = B + (size_t)(k0 + krB) * ldb + n0 + ncB;
            const float4 b0 = *(const float4*)(bp);
            const float4 b1_ = *(const float4*)(bp + 4);
            sBt[ncB + 0][krB] = bfc(b0.x);  sBt[ncB + 1][krB] = bfc(b0.y);
            sBt[ncB + 2][krB] = bfc(b0.z);  sBt[ncB + 3][krB] = bfc(b0.w);
            sBt[ncB + 4][krB] = bfc(b1_.x); sBt[ncB + 5][krB] = bfc(b1_.y);
            sBt[ncB + 6][krB] = bfc(b1_.z); sBt[ncB + 7][krB] = bfc(b1_.w);
        }
        __syncthreads();
        #pragma unroll
        for (int ks = 0; ks < 2; ++ks) {
            const bf16x8 bfrag = *(const bf16x8*)&sBt[wn * 32 + l][ks * 16 + half * 8];
            const bf16x8 afr   = *(const bf16x8*)&sA[wm * 32 + l][ks * 16 + half * 8];
            acc = __builtin_amdgcn_mfma_f32_32x32x16_bf16(afr, bfrag, acc, 0,0,0);
        }
        __syncthreads();
    }
    const int n = n0 + wn * 32 + l;
    #pragma unroll
    for (int r = 0; r < 16; ++r) {
        const int row = (r & 3) + 8 * (r >> 2) + 4 * half;
        C[(size_t)(m0 + wm * 32 + row) * N + n] = bfc(acc[r]);
    }
}

// ---------------------------------------------------------------------------
// MFMA edge kernel. 256 thr (4 waves), grid 1024 (4 blocks/mol),
// __launch_bounds__(256,3) -> target 3 blocks/CU.
// nbase=(blk&3)*8, n = nbase + wave + ni*4, ni in {0,1}.
// ---------------------------------------------------------------------------
__global__ __launch_bounds__(256, 3) void edge_mfma(
    const short* __restrict__ SA, const short* __restrict__ SB,
    const float* __restrict__ pos, short* __restrict__ ebuf,
    const float* __restrict__ W1, const float* __restrict__ b1,
    const float* __restrict__ W2, const float* __restrict__ b2,
    short* __restrict__ Hbuf, float* __restrict__ pdelta)
{
    const int blk = blockIdx.x;
    const int mol = blk >> 2;
    const int nbase = (blk & 3) * 8;
    const int t = threadIdx.x;
    const int wave = t >> 6, lane = t & 63;
    const int l = lane & 31, half = lane >> 5;
    const int node0 = mol * 32;

    __shared__ __align__(16) short sBg[256][72];    // 36 KB (also W2e pre-stage)
    __shared__ __align__(16) short sHdn[4][32][40]; // 10 KB
    __shared__ float sPosS[32][4];
    __shared__ short sW1da[2][256];
    __shared__ short sW2p[256];
    __shared__ float sP[4][32];
    __shared__ float sB1f[256];

    // --- pre-stage W2e cols 321..352 into sBg-aliased scratch, coalesced ---
    // 8192 shorts total; 256 threads -> 32 iterations (BUGFIX from R6: was 16)
    short* sW2e = &sBg[0][0];   // 8192 shorts <= 18432 avail
    for (int i = 0; i < 32; ++i) {
        const int gi = i * 256 + t;
        const int c = gi & 31, j = gi >> 5;
        const int kk = j >> 4, hw = (j >> 3) & 1, jj = j & 7;
        sW2e[(size_t)(kk * 64 + hw * 32 + c) * 8 + jj] = bfc(W2[(size_t)j * 353 + 321 + c]);
    }
    __syncthreads();
    bf16x8 w2efr[16];
    #pragma unroll
    for (int kk = 0; kk < 16; ++kk)
        w2efr[kk] = *(const bf16x8*)&sW2e[(size_t)(kk * 64 + lane) * 8];
    __syncthreads();   // all frags in regs before sBg overwrite

    {   // stage sBg: thread t owns j-column t, all 64 k
        const int j = t;
        for (int k = 0; k < 64; ++k) {
            const short v = (k < 32) ? bfc(W1[(size_t)(512 + k) * 256 + j])
                                     : SA[(size_t)(node0 + (k - 32)) * 256 + j];
            const int slot = ((k >> 3) + 3 * ((j >> 3) & 3)) & 7;
            sBg[j][slot * 8 + (k & 7)] = v;
        }
    }
    sW1da[0][t] = bfc(W1[(size_t)544 * 256 + t]);
    sW1da[1][t] = bfc(W1[(size_t)545 * 256 + t]);
    sW2p[t]     = bfc(W2[(size_t)t * 353 + 320]);
    sB1f[t]     = b1[t];
    if (t < 96) sPosS[t / 3][t % 3] = pos[node0 * 3 + t];

    const float b2e = b2[321 + l];
    const float b2p = b2[320];
    int bslot[4];
    #pragma unroll
    for (int ks = 0; ks < 4; ++ks)
        bslot[ks] = ((ks * 2 + half) + 3 * ((l >> 3) & 3)) & 7;
    __syncthreads();

    for (int ni = 0; ni < 2; ++ni) {
        const int n = nbase + wave + ni * 4;
        const int rrc = (l < 31) ? l : 30;
        const int src = rrc + (rrc >= n ? 1 : 0);
        const float ax = sPosS[n][0],  ay = sPosS[n][1],  az = sPosS[n][2];
        const float bx = sPosS[src][0], by = sPosS[src][1], bz = sPosS[src][2];
        const float rx = ax - bx, ry = ay - by, rz = az - bz;
        const float av = ax * bx + ay * by + az * bz;
        const float dd = sqrtf(fmaxf(rx * rx + ry * ry + rz * rz, 1e-6f));
        const float inv = 1.f / (1.f + dd);
        const float rnx = rx * inv, rny = ry * inv, rnz = rz * inv;

        const short* ebase = ebuf + ((size_t)((mol * 32 + n) * 31 + l)) * 32;
        const bf16x8 fr0 = *(const bf16x8*)(ebase + half * 8);
        const bf16x8 fr1 = *(const bf16x8*)(ebase + 16 + half * 8);
        bf16x8 fr2 = {}, fr3, fr4;
        if (half == 0) { fr2[0] = bfc(dd); fr2[1] = bfc(av); }
        #pragma unroll
        for (int jj = 0; jj < 8; ++jj) {
            fr3[jj] = (half * 8 + jj == src)      ? ONEBF : (short)0;
            fr4[jj] = (16 + half * 8 + jj == src) ? ONEBF : (short)0;
        }

        f32x16 accC = {}, accP = {};
        float Hacc[8];

        const int g = l >> 3, jlow = l & 7;
        #pragma unroll
        for (int cb = 0; cb < 8; ++cb) {
            const float sbv = bf2f(SB[(size_t)(node0 + n) * 256 + cb * 32 + l]) + sB1f[cb * 32 + l];
            f32x16 acc;
            #pragma unroll
            for (int r = 0; r < 16; ++r) acc[r] = sbv;
            {
                const short* brow = &sBg[cb * 32 + l][0];
                acc = __builtin_amdgcn_mfma_f32_32x32x16_bf16(fr0, *(const bf16x8*)(brow + bslot[0]*8), acc, 0,0,0);
                acc = __builtin_amdgcn_mfma_f32_32x32x16_bf16(fr1, *(const bf16x8*)(brow + bslot[1]*8), acc, 0,0,0);
                acc = __builtin_amdgcn_mfma_f32_32x32x16_bf16(fr3, *(const bf16x8*)(brow + bslot[2]*8), acc, 0,0,0);
                acc = __builtin_amdgcn_mfma_f32_32x32x16_bf16(fr4, *(const bf16x8*)(brow + bslot[3]*8), acc, 0,0,0);
                bf16x8 frB2 = {};
                if (half == 0) { frB2[0] = sW1da[0][cb * 32 + l]; frB2[1] = sW1da[1][cb * 32 + l]; }
                acc = __builtin_amdgcn_mfma_f32_32x32x16_bf16(fr2, frB2, acc, 0,0,0);
            }
            float hs = 0.f;
            #pragma unroll
            for (int r = 0; r < 16; ++r) {
                const int e = (r & 3) + 8 * (r >> 2) + 4 * half;
                float h = silu_f(acc[r]);
                if (half == 1 && r == 15) h = 0.f;   // pad row 31
                hs += h;
                sHdn[wave][e][((g + (e >> 3)) & 3) * 8 + jlow] = bfc(h);
            }
            Hacc[cb] = hs;
            #pragma unroll
            for (int q = 0; q < 2; ++q) {
                const int g2 = q * 2 + half;
                const bf16x8 afr  = *(const bf16x8*)&sHdn[wave][l][((g2 + (l >> 3)) & 3) * 8];
                const bf16x8 wpfr = *(const bf16x8*)&sW2p[cb * 32 + q * 16 + half * 8];
                accC = __builtin_amdgcn_mfma_f32_32x32x16_bf16(afr, w2efr[cb * 2 + q], accC, 0,0,0);
                accP = __builtin_amdgcn_mfma_f32_32x32x16_bf16(afr, wpfr, accP, 0,0,0);
            }
        }
        // H (bf16 out)
        #pragma unroll
        for (int cb = 0; cb < 8; ++cb) {
            const float v = Hacc[cb] + __shfl_xor(Hacc[cb], 32, 64);
            if (lane < 32) Hbuf[(size_t)(node0 + n) * 256 + cb * 32 + lane] = bfc(v);
        }
        // p: accP cols equal; lane l==0 of each half scatters its 16 rows
        if (l == 0) {
            #pragma unroll
            for (int q4 = 0; q4 < 4; ++q4) {
                float4 pv = { accP[q4 * 4 + 0], accP[q4 * 4 + 1],
                              accP[q4 * 4 + 2], accP[q4 * 4 + 3] };
                *(float4*)&sP[wave][q4 * 8 + 4 * half] = pv;
            }
        }
        // pd = sum_e rn[e] * (p[e] + b2p); lane l owns e=l (half0 only)
        const float pown = sP[wave][l];
        const float pfull = (half == 0 && l < 31) ? (pown + b2p) : 0.f;
        float pd0 = rnx * pfull, pd1 = rny * pfull, pd2 = rnz * pfull;
        #pragma unroll
        for (int m = 1; m <= 32; m <<= 1) {
            pd0 += __shfl_xor(pd0, m, 64);
            pd1 += __shfl_xor(pd1, m, 64);
            pd2 += __shfl_xor(pd2, m, 64);
        }
        if (lane == 0) {
            pdelta[(size_t)(node0 + n) * 3 + 0] = pd0;
            pdelta[(size_t)(node0 + n) * 3 + 1] = pd1;
            pdelta[(size_t)(node0 + n) * 3 + 2] = pd2;
        }
        // e update (bf16 RMW)
        #pragma unroll
        for (int r = 0; r < 16; ++r) {
            const int e = (r & 3) + 8 * (r >> 2) + 4 * half;
            if (e < 31) {
                short* ep = ebuf + ((size_t)((mol * 32 + n) * 31 + e)) * 32 + l;
                *ep = bfc(bf2f(*ep) + accC[r] + b2e);
            }
        }
    }
}

// ---------------------------------------------------------------------------
// MFMA bond kernel. 256 thr (4 waves), grid 1024, launch_bounds(256,3).
// ---------------------------------------------------------------------------
__global__ __launch_bounds__(256, 3) void bond_mfma(
    const short* __restrict__ U, const float* __restrict__ pos,
    const short* __restrict__ ebuf, const float* __restrict__ We1,
    const float* __restrict__ be1, const float* __restrict__ We2,
    const float* __restrict__ be2, float* __restrict__ outB)
{
    const int blk = blockIdx.x;
    const int mol = blk >> 2;
    const int nbase = (blk & 3) * 8;
    const int t = threadIdx.x;
    const int wave = t >> 6, lane = t & 63;
    const int l = lane & 31, half = lane >> 5;
    const int node0 = mol * 32;

    __shared__ __align__(16) short sBg2[128][72];
    __shared__ __align__(16) short sHdnB[4][32][40];
    __shared__ float sPosS[32][4];
    __shared__ short sWd[128];
    __shared__ float sBe1f[128];

    {   // stage sBg2: j = t & 127, kq = t >> 7 covers k in [kq*32, kq*32+32)
        const int j = t & 127, kq = t >> 7;
        for (int kk = 0; kk < 32; ++kk) {
            const int k = kq * 32 + kk;
            const short v = (k < 32) ? bfc(We1[(size_t)(256 + k) * 128 + j])
                                     : U[(size_t)(node0 + (k - 32)) * 128 + j];
            const int slot = ((k >> 3) + 3 * ((j >> 3) & 3)) & 7;
            sBg2[j][slot * 8 + (k & 7)] = v;
        }
    }
    if (t < 128) { sWd[t] = bfc(We1[(size_t)288 * 128 + t]); sBe1f[t] = be1[t]; }
    if (t < 96) sPosS[t / 3][t % 3] = pos[node0 * 3 + t];

    bf16x8 w2fr[8];
    #pragma unroll
    for (int kk = 0; kk < 8; ++kk) {
        #pragma unroll
        for (int jj = 0; jj < 8; ++jj) {
            const int k = kk * 16 + half * 8 + jj;
            w2fr[kk][jj] = (l < 5) ? bfc(We2[(size_t)k * 5 + l]) : (short)0;
        }
    }
    const float be2v = (l < 5) ? be2[l] : 0.f;
    int bslot[4];
    #pragma unroll
    for (int ks = 0; ks < 4; ++ks)
        bslot[ks] = ((ks * 2 + half) + 3 * ((l >> 3) & 3)) & 7;
    __syncthreads();

    for (int ni = 0; ni < 2; ++ni) {
        const int n = nbase + wave + ni * 4;
        const int rrc = (l < 31) ? l : 30;
        const int src = rrc + (rrc >= n ? 1 : 0);
        const float rx = sPosS[n][0] - sPosS[src][0];
        const float ry = sPosS[n][1] - sPosS[src][1];
        const float rz = sPosS[n][2] - sPosS[src][2];
        const float dd = sqrtf(fmaxf(rx * rx + ry * ry + rz * rz, 1e-6f));

        const short* ebase = ebuf + ((size_t)((mol * 32 + n) * 31 + l)) * 32;
        const bf16x8 fr0 = *(const bf16x8*)(ebase + half * 8);
        const bf16x8 fr1 = *(const bf16x8*)(ebase + 16 + half * 8);
        bf16x8 fr2 = {}, fr3, fr4;
        if (half == 0) fr2[0] = bfc(dd);
        #pragma unroll
        for (int jj = 0; jj < 8; ++jj) {
            fr3[jj] = (half * 8 + jj == src)      ? ONEBF : (short)0;
            fr4[jj] = (16 + half * 8 + jj == src) ? ONEBF : (short)0;
        }

        f32x16 accC = {};
        const int g = l >> 3, jlow = l & 7;
        #pragma unroll
        for (int cb = 0; cb < 4; ++cb) {
            const float uin = bf2f(U[(size_t)(node0 + n) * 128 + cb * 32 + l]) + sBe1f[cb * 32 + l];
            f32x16 acc;
            #pragma unroll
            for (int r = 0; r < 16; ++r) acc[r] = uin;
            {
                const short* brow = &sBg2[cb * 32 + l][0];
                acc = __builtin_amdgcn_mfma_f32_32x32x16_bf16(fr0, *(const bf16x8*)(brow + bslot[0]*8), acc, 0,0,0);
                acc = __builtin_amdgcn_mfma_f32_32x32x16_bf16(fr1, *(const bf16x8*)(brow + bslot[1]*8), acc, 0,0,0);
                acc = __builtin_amdgcn_mfma_f32_32x32x16_bf16(fr3, *(const bf16x8*)(brow + bslot[2]*8), acc, 0,0,0);
                acc = __builtin_amdgcn_mfma_f32_32x32x16_bf16(fr4, *(const bf16x8*)(brow + bslot[3]*8), acc, 0,0,0);
                bf16x8 frWd = {};
                if (half == 0) frWd[0] = sWd[cb * 32 + l];
                acc = __builtin_amdgcn_mfma_f32_32x32x16_bf16(fr2, frWd, acc, 0,0,0);
            }
            #pragma unroll
            for (int r = 0; r < 16; ++r) {
                const int e = (r & 3) + 8 * (r >> 2) + 4 * half;
                sHdnB[wave][e][((g + (e >> 3)) & 3) * 8 + jlow] = bfc(silu_f(acc[r]));
            }
            #pragma unroll
            for (int q = 0; q < 2; ++q) {
                const int g2 = q * 2 + half;
                const bf16x8 afr = *(const bf16x8*)&sHdnB[wave][l][((g2 + (l >> 3)) & 3) * 8];
                accC = __builtin_amdgcn_mfma_f32_32x32x16_bf16(afr, w2fr[cb * 2 + q], accC, 0,0,0);
            }
        }
        if (l < 5) {
            #pragma unroll
            for (int r = 0; r < 16; ++r) {
                const int e = (r & 3) + 8 * (r >> 2) + 4 * half;
                if (e < 31) {
                    const int s_ = e + (e >= n ? 1 : 0);
                    const int ge = (mol * 32 + s_) * 31 + (n - (n > s_ ? 1 : 0));
                    outB[(size_t)ge * 5 + l] = accC[r] + be2v;
                }
            }
        }
    }
}

// ---------------------------------------------------------------------------
__global__ __launch_bounds__(256) void pos_copy(const float* __restrict__ pos,
                                                float* __restrict__ out)
{
    const int i = blockIdx.x * 256 + threadIdx.x;
    out[i] = pos[i];
}

// ---------------------------------------------------------------------------
__global__ __launch_bounds__(256) void atoms_kernel(
    const short* __restrict__ tmp, const float* __restrict__ Wh2,
    const float* __restrict__ bh2, float* __restrict__ outA)
{
    const int gid = blockIdx.x * 256 + threadIdx.x;
    const int n = gid >> 4, o = gid & 15;
    float acc = bh2[o];
    #pragma unroll 8
    for (int k = 0; k < SDIM_; ++k) acc += bf2f(tmp[(size_t)n * SDIM_ + k]) * Wh2[k * NAF_ + o];
    outA[gid] = acc;
}

// ---------------------------------------------------------------------------
extern "C" void kernel_launch(void* const* d_in, const int* in_sizes, int n_in,
                              void* d_out, int out_size, void* d_ws, size_t ws_size,
                              hipStream_t stream) {
    const float* x   = (const float*)d_in[0];
    const float* z   = (const float*)d_in[1];
    const float* rot = (const float*)d_in[2];
    const float* ea  = (const float*)d_in[4];
    const float* Wam = (const float*)d_in[6];
    const float* bam = (const float*)d_in[7];
    const float* Wbm = (const float*)d_in[8];
    const float* bbm = (const float*)d_in[9];
    const float* gW1 = (const float*)d_in[10];
    const float* gb1 = (const float*)d_in[11];
    const float* gW2 = (const float*)d_in[12];
    const float* gb2 = (const float*)d_in[13];
    const float* Wh1 = (const float*)d_in[14];
    const float* bh1 = (const float*)d_in[15];
    const float* Wh2 = (const float*)d_in[16];
    const float* bh2 = (const float*)d_in[17];
    const float* We1 = (const float*)d_in[18];
    const float* be1 = (const float*)d_in[19];
    const float* We2 = (const float*)d_in[20];
    const float* be2 = (const float*)d_in[21];
    float* out = (float*)d_out;

    float* ws  = (float*)d_ws;
    float* s   = ws;                     // 8192*256 fp32
    float* pos = ws + 2097152;           // 8192*3
    short* e   = (short*)(ws + 2121728); // 8192*31*32 bf16
    short* SAh = (short*)(ws + 10248192);// 8192*256 bf16
    short* SBh = (short*)(ws + 12345344);// 8192*256 bf16
    short* Hh  = (short*)(ws + 14442496);// 8192*256 bf16
    float* pd  = ws + 16539648;          // 8192*3
    short* tmph = SAh;                   // reuse after layers
    short* Uh   = Hh;                    // reuse after layers

    node_init<<<NN, 256, 0, stream>>>(x, z, rot, Wam, bam, s, pos);
    edge_init2<<<NN, 256, 0, stream>>>(ea, Wbm, bbm, e);

    for (int l = 0; l < LAYERS_; ++l) {
        const float* W1 = gW1 + (size_t)l * 546 * 256;
        const float* b1 = gb1 + l * 256;
        const float* W2 = gW2 + (size_t)l * 256 * 353;
        const float* b2 = gb2 + l * 353;
        gemm_dual<<<dim3(8, 128), 256, 0, stream>>>(s, W1, W1 + 256 * 256, SAh, SBh);
        edge_mfma<<<4 * N_MOLS, 256, 0, stream>>>(SAh, SBh, pos, e, W1, b1, W2, b2, Hh, pd);
        // s += (H @ W2[:,0:256])/31 + b2[0:256]; fused: pos += pd/31
        gemm_mfma<0,1,1,1,0><<<dim3(4, 128), 256, 0, stream>>>(Hh, W2, s, b2, 256, 256, 353, 1.f / 31.f, pos, pd);
    }

    gemm_mfma<1,0,0,0,1><<<dim3(4, 128), 256, 0, stream>>>(s, Wh1, tmph, bh1, 256, 256, 256, 1.f, nullptr, nullptr);
    atoms_kernel<<<512, 256, 0, stream>>>(tmph, Wh2, bh2, out);

    gemm_mfma<0,0,0,0,1><<<dim3(2, 128), 256, 0, stream>>>(s, We1, Uh, nullptr, 256, 128, 128, 1.f, nullptr, nullptr);
    bond_mfma<<<4 * N_MOLS, 256, 0, stream>>>(Uh, pos, e, We1, be1, We2, be2, out + 131072);

    pos_copy<<<96, 256, 0, stream>>>(pos, out + 131072 + 1269760);
}

// Round 8
// 985.693 us; speedup vs baseline: 1.2599x; 1.2599x over previous
//
#include <hip/hip_runtime.h>
#include <hip/hip_bf16.h>
#include <cstdint>
#include <cstddef>

#define N_MOLS 256
#define N_PER  32
#define NN     8192
#define EDGES  253952
#define SDIM_  256
#define EDIM_  32
#define NAF_   16
#define LAYERS_ 5

typedef __attribute__((ext_vector_type(8)))  short bf16x8;
typedef __attribute__((ext_vector_type(16))) float f32x16;

__device__ __forceinline__ float silu_f(float x) {
    return x / (1.f + __expf(-x));
}
__device__ __forceinline__ short bfc(float f) {
    __hip_bfloat16 h = __float2bfloat16(f);
    return __builtin_bit_cast(short, h);
}
__device__ __forceinline__ float bf2f(short h) {
    union { uint32_t u; float f; } v; v.u = ((uint32_t)(unsigned short)h) << 16; return v.f;
}
#define ONEBF ((short)0x3F80)

// ---------------------------------------------------------------------------
// node init: h = [x|z]@Wam+bam; s = h[:,:256]; pos = rot[mol]@h[:,256:259]
// ---------------------------------------------------------------------------
__global__ __launch_bounds__(256) void node_init(
    const float* __restrict__ x, const float* __restrict__ z,
    const float* __restrict__ rot, const float* __restrict__ Wam,
    const float* __restrict__ bam, float* __restrict__ s, float* __restrict__ pos)
{
    const int n = blockIdx.x, t = threadIdx.x;
    __shared__ float xz[80];
    __shared__ float praw[3];
    if (t < 16)      xz[t] = x[n * 16 + t];
    else if (t < 80) xz[t] = z[n * 64 + (t - 16)];
    __syncthreads();
    float acc = bam[t];
    #pragma unroll 8
    for (int k = 0; k < 80; ++k) acc += xz[k] * Wam[k * 259 + t];
    s[(size_t)n * SDIM_ + t] = acc;
    if (t < 3) {
        const int j2 = 256 + t;
        float a2 = bam[j2];
        for (int k = 0; k < 80; ++k) a2 += xz[k] * Wam[k * 259 + j2];
        praw[t] = a2;
    }
    __syncthreads();
    if (t < 3) {
        const int mol = n >> 5;
        float p = 0.f;
        for (int jj = 0; jj < 3; ++jj) p += rot[mol * 9 + t * 3 + jj] * praw[jj];
        pos[n * 3 + t] = p;
    }
}

// ---------------------------------------------------------------------------
// edge feature init (bf16 out), tgt-major: e[((mol*32+n)*31+rr)*32+c]
// ---------------------------------------------------------------------------
__global__ __launch_bounds__(256) void edge_init2(
    const float* __restrict__ ea, const float* __restrict__ Wbm,
    const float* __restrict__ bbm, short* __restrict__ ebuf)
{
    const int tile = blockIdx.x;          // mol*32 + n
    const int mol = tile >> 5, n = tile & 31;
    const int t = threadIdx.x;
    for (int i = t; i < 31 * 32; i += 256) {
        const int rr = i >> 5, c = i & 31;
        const int s_ = rr + (rr >= n ? 1 : 0);
        const int ge = (mol * 32 + s_) * 31 + (n - (n > s_ ? 1 : 0));
        float acc = bbm[c];
        #pragma unroll
        for (int k = 0; k < 5; ++k) acc += ea[(size_t)ge * 5 + k] * Wbm[k * 32 + c];
        ebuf[(size_t)tile * 31 * 32 + i] = bfc(acc);
    }
}

// ---------------------------------------------------------------------------
// bf16 MFMA GEMM (R5 version): 128x64 tile, 4 waves.
// ABF: A bf16; OUTBF: C bf16; POSTAIL: blocks (x==1,y<48) do pos += pd/31.
// ---------------------------------------------------------------------------
template<int ACT, int ACCUM, int POSTAIL, int ABF, int OUTBF>
__global__ __launch_bounds__(256) void gemm_mfma(
    const void* __restrict__ Av, const float* __restrict__ B,
    void* __restrict__ Cv, const float* __restrict__ bias,
    int K, int N, int ldb, float alpha,
    float* __restrict__ pos, const float* __restrict__ pd)
{
    const int n0 = blockIdx.x * 64, m0 = blockIdx.y * 128;
    const int t = threadIdx.x;
    const int wave = t >> 6, lane = t & 63;
    const int l = lane & 31, half = lane >> 5;
    const int wm = wave & 1, wn = wave >> 1;
    __shared__ __align__(16) short sA[128][40];
    __shared__ __align__(16) short sBt[64][40];
    f32x16 acc0 = {}, acc1 = {};
    const int mA = t >> 1, koA = (t & 1) * 16;
    const int krB = t >> 3, ncB = (t & 7) * 8;
    for (int k0 = 0; k0 < K; k0 += 32) {
        if (ABF) {
            const short* ap = (const short*)Av + (size_t)(m0 + mA) * K + k0 + koA;
            *(bf16x8*)&sA[mA][koA]     = *(const bf16x8*)(ap);
            *(bf16x8*)&sA[mA][koA + 8] = *(const bf16x8*)(ap + 8);
        } else {
            const float* ap = (const float*)Av + (size_t)(m0 + mA) * K + k0 + koA;
            const float4 a0 = *(const float4*)(ap);
            const float4 a1 = *(const float4*)(ap + 4);
            const float4 a2 = *(const float4*)(ap + 8);
            const float4 a3 = *(const float4*)(ap + 12);
            bf16x8 p0, p1;
            p0[0]=bfc(a0.x); p0[1]=bfc(a0.y); p0[2]=bfc(a0.z); p0[3]=bfc(a0.w);
            p0[4]=bfc(a1.x); p0[5]=bfc(a1.y); p0[6]=bfc(a1.z); p0[7]=bfc(a1.w);
            p1[0]=bfc(a2.x); p1[1]=bfc(a2.y); p1[2]=bfc(a2.z); p1[3]=bfc(a2.w);
            p1[4]=bfc(a3.x); p1[5]=bfc(a3.y); p1[6]=bfc(a3.z); p1[7]=bfc(a3.w);
            *(bf16x8*)&sA[mA][koA]     = p0;
            *(bf16x8*)&sA[mA][koA + 8] = p1;
        }
        {
            const float* bp = B + (size_t)(k0 + krB) * ldb + n0 + ncB;
            const float4 b0 = *(const float4*)(bp);
            const float4 b1_ = *(const float4*)(bp + 4);
            sBt[ncB + 0][krB] = bfc(b0.x);  sBt[ncB + 1][krB] = bfc(b0.y);
            sBt[ncB + 2][krB] = bfc(b0.z);  sBt[ncB + 3][krB] = bfc(b0.w);
            sBt[ncB + 4][krB] = bfc(b1_.x); sBt[ncB + 5][krB] = bfc(b1_.y);
            sBt[ncB + 6][krB] = bfc(b1_.z); sBt[ncB + 7][krB] = bfc(b1_.w);
        }
        __syncthreads();
        #pragma unroll
        for (int ks = 0; ks < 2; ++ks) {
            const bf16x8 bfrag = *(const bf16x8*)&sBt[wn * 32 + l][ks * 16 + half * 8];
            const bf16x8 afr0  = *(const bf16x8*)&sA[wm * 64 + l][ks * 16 + half * 8];
            const bf16x8 afr1  = *(const bf16x8*)&sA[wm * 64 + 32 + l][ks * 16 + half * 8];
            acc0 = __builtin_amdgcn_mfma_f32_32x32x16_bf16(afr0, bfrag, acc0, 0,0,0);
            acc1 = __builtin_amdgcn_mfma_f32_32x32x16_bf16(afr1, bfrag, acc1, 0,0,0);
        }
        __syncthreads();
    }
    const int n = n0 + wn * 32 + l;
    const float bv = bias ? bias[n] : 0.f;
    #pragma unroll
    for (int r = 0; r < 16; ++r) {
        const int row = (r & 3) + 8 * (r >> 2) + 4 * half;
        {
            const int m = m0 + wm * 64 + row;
            float v = alpha * acc0[r] + bv;
            if (ACT) v = silu_f(v);
            if (OUTBF) ((short*)Cv)[(size_t)m * N + n] = bfc(v);
            else if (ACCUM) ((float*)Cv)[(size_t)m * N + n] += v;
            else            ((float*)Cv)[(size_t)m * N + n] = v;
        }
        {
            const int m = m0 + wm * 64 + 32 + row;
            float v = alpha * acc1[r] + bv;
            if (ACT) v = silu_f(v);
            if (OUTBF) ((short*)Cv)[(size_t)m * N + n] = bfc(v);
            else if (ACCUM) ((float*)Cv)[(size_t)m * N + n] += v;
            else            ((float*)Cv)[(size_t)m * N + n] = v;
        }
    }
    if (POSTAIL && blockIdx.x == 1 && blockIdx.y < 48) {
        const int i = (blockIdx.y * 256 + t) * 2;
        pos[i]     += pd[i]     * (1.f / 31.f);
        pos[i + 1] += pd[i + 1] * (1.f / 31.f);
    }
}

// ---------------------------------------------------------------------------
// Dual GEMM (bf16 out, R5 version): SA = s@W1a, SB = s@W1b. grid (8,64).
// ---------------------------------------------------------------------------
__global__ __launch_bounds__(256) void gemm_dual(
    const float* __restrict__ A, const float* __restrict__ B0,
    const float* __restrict__ B1, short* __restrict__ C0, short* __restrict__ C1)
{
    const int K = 256, N = 256, ldb = 256;
    const float* B = (blockIdx.x < 4) ? B0 : B1;
    short* C = (blockIdx.x < 4) ? C0 : C1;
    const int n0 = (blockIdx.x & 3) * 64, m0 = blockIdx.y * 128;
    const int t = threadIdx.x;
    const int wave = t >> 6, lane = t & 63;
    const int l = lane & 31, half = lane >> 5;
    const int wm = wave & 1, wn = wave >> 1;
    __shared__ __align__(16) short sA[128][40];
    __shared__ __align__(16) short sBt[64][40];
    f32x16 acc0 = {}, acc1 = {};
    const int mA = t >> 1, koA = (t & 1) * 16;
    const int krB = t >> 3, ncB = (t & 7) * 8;
    for (int k0 = 0; k0 < K; k0 += 32) {
        {
            const float* ap = A + (size_t)(m0 + mA) * K + k0 + koA;
            const float4 a0 = *(const float4*)(ap);
            const float4 a1 = *(const float4*)(ap + 4);
            const float4 a2 = *(const float4*)(ap + 8);
            const float4 a3 = *(const float4*)(ap + 12);
            bf16x8 p0, p1;
            p0[0]=bfc(a0.x); p0[1]=bfc(a0.y); p0[2]=bfc(a0.z); p0[3]=bfc(a0.w);
            p0[4]=bfc(a1.x); p0[5]=bfc(a1.y); p0[6]=bfc(a1.z); p0[7]=bfc(a1.w);
            p1[0]=bfc(a2.x); p1[1]=bfc(a2.y); p1[2]=bfc(a2.z); p1[3]=bfc(a2.w);
            p1[4]=bfc(a3.x); p1[5]=bfc(a3.y); p1[6]=bfc(a3.z); p1[7]=bfc(a3.w);
            *(bf16x8*)&sA[mA][koA]     = p0;
            *(bf16x8*)&sA[mA][koA + 8] = p1;
        }
        {
            const float* bp = B + (size_t)(k0 + krB) * ldb + n0 + ncB;
            const float4 b0 = *(const float4*)(bp);
            const float4 b1_ = *(const float4*)(bp + 4);
            sBt[ncB + 0][krB] = bfc(b0.x);  sBt[ncB + 1][krB] = bfc(b0.y);
            sBt[ncB + 2][krB] = bfc(b0.z);  sBt[ncB + 3][krB] = bfc(b0.w);
            sBt[ncB + 4][krB] = bfc(b1_.x); sBt[ncB + 5][krB] = bfc(b1_.y);
            sBt[ncB + 6][krB] = bfc(b1_.z); sBt[ncB + 7][krB] = bfc(b1_.w);
        }
        __syncthreads();
        #pragma unroll
        for (int ks = 0; ks < 2; ++ks) {
            const bf16x8 bfrag = *(const bf16x8*)&sBt[wn * 32 + l][ks * 16 + half * 8];
            const bf16x8 afr0  = *(const bf16x8*)&sA[wm * 64 + l][ks * 16 + half * 8];
            const bf16x8 afr1  = *(const bf16x8*)&sA[wm * 64 + 32 + l][ks * 16 + half * 8];
            acc0 = __builtin_amdgcn_mfma_f32_32x32x16_bf16(afr0, bfrag, acc0, 0,0,0);
            acc1 = __builtin_amdgcn_mfma_f32_32x32x16_bf16(afr1, bfrag, acc1, 0,0,0);
        }
        __syncthreads();
    }
    const int n = n0 + wn * 32 + l;
    #pragma unroll
    for (int r = 0; r < 16; ++r) {
        const int row = (r & 3) + 8 * (r >> 2) + 4 * half;
        C[(size_t)(m0 + wm * 64 + row) * N + n]      = bfc(acc0[r]);
        C[(size_t)(m0 + wm * 64 + 32 + row) * N + n] = bfc(acc1[r]);
    }
}

// ---------------------------------------------------------------------------
// MFMA edge kernel (R5 structure: grid 512, 512 thr, 16 tiles/block).
// R8 change: W2e fragments stay in PERSISTENT LDS (frees 64 VGPRs);
// b1/w1d/w1a read from LDS per-cb; __launch_bounds__(512,4) to force
// <=128 regs -> 2 blocks/CU.
// ---------------------------------------------------------------------------
__global__ __launch_bounds__(512, 4) void edge_mfma(
    const short* __restrict__ SA, const short* __restrict__ SB,
    const float* __restrict__ pos, short* __restrict__ ebuf,
    const float* __restrict__ W1, const float* __restrict__ b1,
    const float* __restrict__ W2, const float* __restrict__ b2,
    short* __restrict__ Hbuf, float* __restrict__ pdelta)
{
    const int blk = blockIdx.x;
    const int mol = blk >> 1;
    const int nbase = (blk & 1) * 16;
    const int t = threadIdx.x;
    const int wave = t >> 6, lane = t & 63;
    const int l = lane & 31, half = lane >> 5;
    const int node0 = mol * 32;

    __shared__ __align__(16) short sBg[256][72];    // 36 KB
    __shared__ __align__(16) short sHdn[8][32][40]; // 20 KB
    __shared__ __align__(16) short sW2e[8192];      // 16 KB persistent
    __shared__ float sPosS[32][4];
    __shared__ short sW1da[2][256];
    __shared__ short sW2p[256];
    __shared__ float sP[8][32];
    __shared__ float sB1f[256];

    // stage W2e cols 321..352 (persistent); 512 thr x 16 iters = 8192
    for (int i = 0; i < 16; ++i) {
        const int gi = i * 512 + t;
        const int c = gi & 31, j = gi >> 5;
        const int kk = j >> 4, hw = (j >> 3) & 1, jj = j & 7;
        sW2e[(size_t)(kk * 64 + hw * 32 + c) * 8 + jj] = bfc(W2[(size_t)j * 353 + 321 + c]);
    }
    {   // stage sBg: k0..31 = W1c (fp32->bf16), k32..63 = SA rows (bf16 copy)
        const int j = t & 255;
        const int k0s = (t >> 8) * 32;
        for (int kk = 0; kk < 32; ++kk) {
            const int k = k0s + kk;
            const short v = (k < 32) ? bfc(W1[(size_t)(512 + k) * 256 + j])
                                     : SA[(size_t)(node0 + (k - 32)) * 256 + j];
            const int slot = ((k >> 3) + 3 * ((j >> 3) & 3)) & 7;
            sBg[j][slot * 8 + (k & 7)] = v;
        }
    }
    if (t < 256) {
        sW1da[0][t] = bfc(W1[(size_t)544 * 256 + t]);
        sW1da[1][t] = bfc(W1[(size_t)545 * 256 + t]);
        sW2p[t]     = bfc(W2[(size_t)t * 353 + 320]);
        sB1f[t]     = b1[t];
    }
    if (t < 96) sPosS[t / 3][t % 3] = pos[node0 * 3 + t];

    const float b2e = b2[321 + l];
    const float b2p = b2[320];
    int bslot[4];
    #pragma unroll
    for (int ks = 0; ks < 4; ++ks)
        bslot[ks] = ((ks * 2 + half) + 3 * ((l >> 3) & 3)) & 7;
    __syncthreads();

    for (int ni = 0; ni < 2; ++ni) {
        const int n = nbase + wave + ni * 8;
        const int rrc = (l < 31) ? l : 30;
        const int src = rrc + (rrc >= n ? 1 : 0);
        const float ax = sPosS[n][0],  ay = sPosS[n][1],  az = sPosS[n][2];
        const float bx = sPosS[src][0], by = sPosS[src][1], bz = sPosS[src][2];
        const float rx = ax - bx, ry = ay - by, rz = az - bz;
        const float av = ax * bx + ay * by + az * bz;
        const float dd = sqrtf(fmaxf(rx * rx + ry * ry + rz * rz, 1e-6f));
        const float inv = 1.f / (1.f + dd);
        const float rnx = rx * inv, rny = ry * inv, rnz = rz * inv;

        const short* ebase = ebuf + ((size_t)((mol * 32 + n) * 31 + l)) * 32;
        const bf16x8 fr0 = *(const bf16x8*)(ebase + half * 8);
        const bf16x8 fr1 = *(const bf16x8*)(ebase + 16 + half * 8);
        bf16x8 fr2 = {}, fr3, fr4;
        if (half == 0) { fr2[0] = bfc(dd); fr2[1] = bfc(av); }
        #pragma unroll
        for (int jj = 0; jj < 8; ++jj) {
            fr3[jj] = (half * 8 + jj == src)      ? ONEBF : (short)0;
            fr4[jj] = (16 + half * 8 + jj == src) ? ONEBF : (short)0;
        }

        f32x16 accC = {}, accP = {};
        float Hacc[8];

        const int g = l >> 3, jlow = l & 7;
        #pragma unroll
        for (int cb = 0; cb < 8; ++cb) {
            const float sbv = bf2f(SB[(size_t)(node0 + n) * 256 + cb * 32 + l]) + sB1f[cb * 32 + l];
            f32x16 acc;
            #pragma unroll
            for (int r = 0; r < 16; ++r) acc[r] = sbv;
            {
                const short* brow = &sBg[cb * 32 + l][0];
                acc = __builtin_amdgcn_mfma_f32_32x32x16_bf16(fr0, *(const bf16x8*)(brow + bslot[0]*8), acc, 0,0,0);
                acc = __builtin_amdgcn_mfma_f32_32x32x16_bf16(fr1, *(const bf16x8*)(brow + bslot[1]*8), acc, 0,0,0);
                acc = __builtin_amdgcn_mfma_f32_32x32x16_bf16(fr3, *(const bf16x8*)(brow + bslot[2]*8), acc, 0,0,0);
                acc = __builtin_amdgcn_mfma_f32_32x32x16_bf16(fr4, *(const bf16x8*)(brow + bslot[3]*8), acc, 0,0,0);
                bf16x8 frB2 = {};
                if (half == 0) { frB2[0] = sW1da[0][cb * 32 + l]; frB2[1] = sW1da[1][cb * 32 + l]; }
                acc = __builtin_amdgcn_mfma_f32_32x32x16_bf16(fr2, frB2, acc, 0,0,0);
            }
            float hs = 0.f;
            #pragma unroll
            for (int r = 0; r < 16; ++r) {
                const int e = (r & 3) + 8 * (r >> 2) + 4 * half;
                float h = silu_f(acc[r]);
                if (half == 1 && r == 15) h = 0.f;   // pad row 31
                hs += h;
                sHdn[wave][e][((g + (e >> 3)) & 3) * 8 + jlow] = bfc(h);
            }
            Hacc[cb] = hs;
            #pragma unroll
            for (int q = 0; q < 2; ++q) {
                const int g2 = q * 2 + half;
                const bf16x8 afr  = *(const bf16x8*)&sHdn[wave][l][((g2 + (l >> 3)) & 3) * 8];
                const bf16x8 wefr = *(const bf16x8*)&sW2e[(size_t)(((cb * 2 + q) * 64) + lane) * 8];
                const bf16x8 wpfr = *(const bf16x8*)&sW2p[cb * 32 + q * 16 + half * 8];
                accC = __builtin_amdgcn_mfma_f32_32x32x16_bf16(afr, wefr, accC, 0,0,0);
                accP = __builtin_amdgcn_mfma_f32_32x32x16_bf16(afr, wpfr, accP, 0,0,0);
            }
        }
        // H (bf16 out)
        #pragma unroll
        for (int cb = 0; cb < 8; ++cb) {
            const float v = Hacc[cb] + __shfl_xor(Hacc[cb], 32, 64);
            if (lane < 32) Hbuf[(size_t)(node0 + n) * 256 + cb * 32 + lane] = bfc(v);
        }
        // p: accP cols equal; lane l==0 of each half scatters its 16 rows
        if (l == 0) {
            #pragma unroll
            for (int q4 = 0; q4 < 4; ++q4) {
                float4 pv = { accP[q4 * 4 + 0], accP[q4 * 4 + 1],
                              accP[q4 * 4 + 2], accP[q4 * 4 + 3] };
                *(float4*)&sP[wave][q4 * 8 + 4 * half] = pv;
            }
        }
        // pd = sum_e rn[e] * (p[e] + b2p); lane l owns e=l (half0 only)
        const float pown = sP[wave][l];
        const float pfull = (half == 0 && l < 31) ? (pown + b2p) : 0.f;
        float pd0 = rnx * pfull, pd1 = rny * pfull, pd2 = rnz * pfull;
        #pragma unroll
        for (int m = 1; m <= 32; m <<= 1) {
            pd0 += __shfl_xor(pd0, m, 64);
            pd1 += __shfl_xor(pd1, m, 64);
            pd2 += __shfl_xor(pd2, m, 64);
        }
        if (lane == 0) {
            pdelta[(size_t)(node0 + n) * 3 + 0] = pd0;
            pdelta[(size_t)(node0 + n) * 3 + 1] = pd1;
            pdelta[(size_t)(node0 + n) * 3 + 2] = pd2;
        }
        // e update (bf16 RMW)
        #pragma unroll
        for (int r = 0; r < 16; ++r) {
            const int e = (r & 3) + 8 * (r >> 2) + 4 * half;
            if (e < 31) {
                short* ep = ebuf + ((size_t)((mol * 32 + n) * 31 + e)) * 32 + l;
                *ep = bfc(bf2f(*ep) + accC[r] + b2e);
            }
        }
    }
}

// ---------------------------------------------------------------------------
// MFMA bond kernel (R5 version: grid 512, 512 thr).
// ---------------------------------------------------------------------------
__global__ __launch_bounds__(512) void bond_mfma(
    const short* __restrict__ U, const float* __restrict__ pos,
    const short* __restrict__ ebuf, const float* __restrict__ We1,
    const float* __restrict__ be1, const float* __restrict__ We2,
    const float* __restrict__ be2, float* __restrict__ outB)
{
    const int blk = blockIdx.x;
    const int mol = blk >> 1;
    const int nbase = (blk & 1) * 16;
    const int t = threadIdx.x;
    const int wave = t >> 6, lane = t & 63;
    const int l = lane & 31, half = lane >> 5;
    const int node0 = mol * 32;

    __shared__ __align__(16) short sBg2[128][72];
    __shared__ __align__(16) short sHdnB[8][32][40];
    __shared__ float sPosS[32][4];
    __shared__ short sWd[128];

    {
        const int j = t & 127, kq = t >> 7;
        for (int kk = 0; kk < 16; ++kk) {
            const int k = kq * 16 + kk;
            const short v = (k < 32) ? bfc(We1[(size_t)(256 + k) * 128 + j])
                                     : U[(size_t)(node0 + (k - 32)) * 128 + j];
            const int slot = ((k >> 3) + 3 * ((j >> 3) & 3)) & 7;
            sBg2[j][slot * 8 + (k & 7)] = v;
        }
    }
    if (t < 128) sWd[t] = bfc(We1[(size_t)288 * 128 + t]);
    if (t < 96) sPosS[t / 3][t % 3] = pos[node0 * 3 + t];

    bf16x8 w2fr[8];
    #pragma unroll
    for (int kk = 0; kk < 8; ++kk) {
        #pragma unroll
        for (int jj = 0; jj < 8; ++jj) {
            const int k = kk * 16 + half * 8 + jj;
            w2fr[kk][jj] = (l < 5) ? bfc(We2[(size_t)k * 5 + l]) : (short)0;
        }
    }
    float be1v[4];
    #pragma unroll
    for (int cb = 0; cb < 4; ++cb) be1v[cb] = be1[cb * 32 + l];
    const float be2v = (l < 5) ? be2[l] : 0.f;
    int bslot[4];
    #pragma unroll
    for (int ks = 0; ks < 4; ++ks)
        bslot[ks] = ((ks * 2 + half) + 3 * ((l >> 3) & 3)) & 7;
    __syncthreads();

    for (int ni = 0; ni < 2; ++ni) {
        const int n = nbase + wave + ni * 8;
        const int rrc = (l < 31) ? l : 30;
        const int src = rrc + (rrc >= n ? 1 : 0);
        const float rx = sPosS[n][0] - sPosS[src][0];
        const float ry = sPosS[n][1] - sPosS[src][1];
        const float rz = sPosS[n][2] - sPosS[src][2];
        const float dd = sqrtf(fmaxf(rx * rx + ry * ry + rz * rz, 1e-6f));

        const short* ebase = ebuf + ((size_t)((mol * 32 + n) * 31 + l)) * 32;
        const bf16x8 fr0 = *(const bf16x8*)(ebase + half * 8);
        const bf16x8 fr1 = *(const bf16x8*)(ebase + 16 + half * 8);
        bf16x8 fr2 = {}, fr3, fr4;
        if (half == 0) fr2[0] = bfc(dd);
        #pragma unroll
        for (int jj = 0; jj < 8; ++jj) {
            fr3[jj] = (half * 8 + jj == src)      ? ONEBF : (short)0;
            fr4[jj] = (16 + half * 8 + jj == src) ? ONEBF : (short)0;
        }

        f32x16 accC = {};
        const int g = l >> 3, jlow = l & 7;
        #pragma unroll
        for (int cb = 0; cb < 4; ++cb) {
            const float uin = bf2f(U[(size_t)(node0 + n) * 128 + cb * 32 + l]) + be1v[cb];
            f32x16 acc;
            #pragma unroll
            for (int r = 0; r < 16; ++r) acc[r] = uin;
            {
                const short* brow = &sBg2[cb * 32 + l][0];
                acc = __builtin_amdgcn_mfma_f32_32x32x16_bf16(fr0, *(const bf16x8*)(brow + bslot[0]*8), acc, 0,0,0);
                acc = __builtin_amdgcn_mfma_f32_32x32x16_bf16(fr1, *(const bf16x8*)(brow + bslot[1]*8), acc, 0,0,0);
                acc = __builtin_amdgcn_mfma_f32_32x32x16_bf16(fr3, *(const bf16x8*)(brow + bslot[2]*8), acc, 0,0,0);
                acc = __builtin_amdgcn_mfma_f32_32x32x16_bf16(fr4, *(const bf16x8*)(brow + bslot[3]*8), acc, 0,0,0);
                bf16x8 frWd = {};
                if (half == 0) frWd[0] = sWd[cb * 32 + l];
                acc = __builtin_amdgcn_mfma_f32_32x32x16_bf16(fr2, frWd, acc, 0,0,0);
            }
            #pragma unroll
            for (int r = 0; r < 16; ++r) {
                const int e = (r & 3) + 8 * (r >> 2) + 4 * half;
                sHdnB[wave][e][((g + (e >> 3)) & 3) * 8 + jlow] = bfc(silu_f(acc[r]));
            }
            #pragma unroll
            for (int q = 0; q < 2; ++q) {
                const int g2 = q * 2 + half;
                const bf16x8 afr = *(const bf16x8*)&sHdnB[wave][l][((g2 + (l >> 3)) & 3) * 8];
                accC = __builtin_amdgcn_mfma_f32_32x32x16_bf16(afr, w2fr[cb * 2 + q], accC, 0,0,0);
            }
        }
        if (l < 5) {
            #pragma unroll
            for (int r = 0; r < 16; ++r) {
                const int e = (r & 3) + 8 * (r >> 2) + 4 * half;
                if (e < 31) {
                    const int s_ = e + (e >= n ? 1 : 0);
                    const int ge = (mol * 32 + s_) * 31 + (n - (n > s_ ? 1 : 0));
                    outB[(size_t)ge * 5 + l] = accC[r] + be2v;
                }
            }
        }
    }
}

// ---------------------------------------------------------------------------
__global__ __launch_bounds__(256) void pos_copy(const float* __restrict__ pos,
                                                float* __restrict__ out)
{
    const int i = blockIdx.x * 256 + threadIdx.x;
    out[i] = pos[i];
}

// ---------------------------------------------------------------------------
__global__ __launch_bounds__(256) void atoms_kernel(
    const short* __restrict__ tmp, const float* __restrict__ Wh2,
    const float* __restrict__ bh2, float* __restrict__ outA)
{
    const int gid = blockIdx.x * 256 + threadIdx.x;
    const int n = gid >> 4, o = gid & 15;
    float acc = bh2[o];
    #pragma unroll 8
    for (int k = 0; k < SDIM_; ++k) acc += bf2f(tmp[(size_t)n * SDIM_ + k]) * Wh2[k * NAF_ + o];
    outA[gid] = acc;
}

// ---------------------------------------------------------------------------
extern "C" void kernel_launch(void* const* d_in, const int* in_sizes, int n_in,
                              void* d_out, int out_size, void* d_ws, size_t ws_size,
                              hipStream_t stream) {
    const float* x   = (const float*)d_in[0];
    const float* z   = (const float*)d_in[1];
    const float* rot = (const float*)d_in[2];
    const float* ea  = (const float*)d_in[4];
    const float* Wam = (const float*)d_in[6];
    const float* bam = (const float*)d_in[7];
    const float* Wbm = (const float*)d_in[8];
    const float* bbm = (const float*)d_in[9];
    const float* gW1 = (const float*)d_in[10];
    const float* gb1 = (const float*)d_in[11];
    const float* gW2 = (const float*)d_in[12];
    const float* gb2 = (const float*)d_in[13];
    const float* Wh1 = (const float*)d_in[14];
    const float* bh1 = (const float*)d_in[15];
    const float* Wh2 = (const float*)d_in[16];
    const float* bh2 = (const float*)d_in[17];
    const float* We1 = (const float*)d_in[18];
    const float* be1 = (const float*)d_in[19];
    const float* We2 = (const float*)d_in[20];
    const float* be2 = (const float*)d_in[21];
    float* out = (float*)d_out;

    float* ws  = (float*)d_ws;
    float* s   = ws;                     // 8192*256 fp32
    float* pos = ws + 2097152;           // 8192*3
    short* e   = (short*)(ws + 2121728); // 8192*31*32 bf16
    short* SAh = (short*)(ws + 10248192);// 8192*256 bf16
    short* SBh = (short*)(ws + 12345344);// 8192*256 bf16
    short* Hh  = (short*)(ws + 14442496);// 8192*256 bf16
    float* pd  = ws + 16539648;          // 8192*3
    short* tmph = SAh;                   // reuse after layers
    short* Uh   = Hh;                    // reuse after layers

    node_init<<<NN, 256, 0, stream>>>(x, z, rot, Wam, bam, s, pos);
    edge_init2<<<NN, 256, 0, stream>>>(ea, Wbm, bbm, e);

    for (int l = 0; l < LAYERS_; ++l) {
        const float* W1 = gW1 + (size_t)l * 546 * 256;
        const float* b1 = gb1 + l * 256;
        const float* W2 = gW2 + (size_t)l * 256 * 353;
        const float* b2 = gb2 + l * 353;
        gemm_dual<<<dim3(8, 64), 256, 0, stream>>>(s, W1, W1 + 256 * 256, SAh, SBh);
        edge_mfma<<<2 * N_MOLS, 512, 0, stream>>>(SAh, SBh, pos, e, W1, b1, W2, b2, Hh, pd);
        // s += (H @ W2[:,0:256])/31 + b2[0:256]; fused: pos += pd/31
        gemm_mfma<0,1,1,1,0><<<dim3(4, 64), 256, 0, stream>>>(Hh, W2, s, b2, 256, 256, 353, 1.f / 31.f, pos, pd);
    }

    gemm_mfma<1,0,0,0,1><<<dim3(4, 64), 256, 0, stream>>>(s, Wh1, tmph, bh1, 256, 256, 256, 1.f, nullptr, nullptr);
    atoms_kernel<<<512, 256, 0, stream>>>(tmph, Wh2, bh2, out);

    gemm_mfma<0,0,0,0,1><<<dim3(2, 64), 256, 0, stream>>>(s, We1, Uh, nullptr, 256, 128, 128, 1.f, nullptr, nullptr);
    bond_mfma<<<2 * N_MOLS, 512, 0, stream>>>(Uh, pos, e, We1, be1, We2, be2, out + 131072);

    pos_copy<<<96, 256, 0, stream>>>(pos, out + 131072 + 1269760);
}